// Round 5
// baseline (853.241 us; speedup 1.0000x reference)
//
#include <hip/hip_runtime.h>
#include <hip/hip_bf16.h>
#include <climits>
#include <cstdint>

#define NB 65536   // batch
#define NP 1024    // prototypes
#define ND 512     // embed dim

// Hi-only f16 GEMM error (scaled units) has std ~4e-4; 4e-3 is ~7 sigma on the
// pairwise difference -> rows with approx top-2 gap below this get exact fp32
// recompute. Expected flagged rows ~1-2% of B.
#define MARGIN 4e-3f

typedef _Float16 f16x8 __attribute__((ext_vector_type(8)));
typedef float    f32x4 __attribute__((ext_vector_type(4)));

// ---------------------------------------------------------------------------
// rnorm[p] = 1 / max(||c_p||, 1e-12). One wave per row.
// ---------------------------------------------------------------------------
__global__ void centroid_rnorm_kernel(const float* __restrict__ cent,
                                      float* __restrict__ rnorm) {
    const int row  = blockIdx.x * 4 + (threadIdx.x >> 6);
    const int lane = threadIdx.x & 63;
    const float4* cr = (const float4*)(cent + (size_t)row * ND);
    float4 a = cr[2 * lane];
    float4 b = cr[2 * lane + 1];
    float s = a.x * a.x + a.y * a.y + a.z * a.z + a.w * a.w
            + b.x * b.x + b.y * b.y + b.z * b.z + b.w * b.w;
#pragma unroll
    for (int off = 32; off > 0; off >>= 1)
        s += __shfl_down(s, off, 64);
    if (lane == 0)
        rnorm[row] = 1.0f / fmaxf(sqrtf(s), 1e-12f);
}

// ---------------------------------------------------------------------------
// fp32 -> f16 (hi only) converters.
// Qp layout: 65536 x 512 f16.   Cp layout: 1024 x 512 f16.
// ---------------------------------------------------------------------------
__global__ void convertQ_kernel(const float* __restrict__ Q,
                                _Float16* __restrict__ Qp) {
    const size_t t = (size_t)blockIdx.x * 256 + threadIdx.x;  // 8 elems/thread
    const size_t base = t * 8;
    const float4* s = (const float4*)(Q + base);
    float4 x0 = s[0], x1 = s[1];
    float xs[8] = {x0.x, x0.y, x0.z, x0.w, x1.x, x1.y, x1.z, x1.w};
    f16x8 hi;
#pragma unroll
    for (int i = 0; i < 8; ++i)
        hi[i] = (_Float16)xs[i];
    *(f16x8*)(Qp + base) = hi;
}

__global__ void convertC_kernel(const float* __restrict__ C,
                                _Float16* __restrict__ Cp) {
    const size_t t = (size_t)blockIdx.x * 256 + threadIdx.x;
    const size_t base = t * 8;
    const float4* s = (const float4*)(C + base);
    float4 x0 = s[0], x1 = s[1];
    float xs[8] = {x0.x, x0.y, x0.z, x0.w, x1.x, x1.y, x1.z, x1.w};
    f16x8 hi;
#pragma unroll
    for (int i = 0; i < 8; ++i)
        hi[i] = (_Float16)xs[i];
    *(f16x8*)(Cp + base) = hi;
}

// ---------------------------------------------------------------------------
// 1-wave register MFMA GEMM: no LDS, no barriers. Each 64-thread block (one
// wave) owns a 64x64 output tile; A and B fragments are read directly from
// global (L2-cached: B is 1 MB = L2-resident; A-panel is read by 16 n-tiles
// via L2). acc[4][4] f32x4 in VGPRs. K-loop: 16 steps of 32 = 8 dwordx4
// loads + 16 MFMA, fully independent waves -> latency hidden by occupancy
// (no LDS => 3+ waves/SIMD of independent work).
//
// Grid 16384 = 1024 m-tiles x 16 n-tiles, XCD-swizzled: xcd = bid&7 owns
// m-tiles {xcd, xcd+8, ...} with n iterating fastest, so each A-panel is
// HBM-fetched by exactly one XCD and L2-hits for its 16 n-tiles.
// Per-row top-2 over the tile's 64 cols -> partial {v1,i1,v2} (16/row).
// ---------------------------------------------------------------------------
__launch_bounds__(64, 3)
__global__ void gemm_top2_kernel(const _Float16* __restrict__ Qp,
                                 const _Float16* __restrict__ Cp,
                                 const float* __restrict__ rnorm,
                                 float* __restrict__ pv1,
                                 int*   __restrict__ pi1,
                                 float* __restrict__ pv2) {
    const int lane = threadIdx.x;          // 0..63 (one wave)
    const int quad = lane >> 4, l15 = lane & 15;

    const int bid = blockIdx.x;
    const int x = bid & 7, j = bid >> 3;
    const int nb  = j & 15;                // n-tile 0..15
    const int mtb = (j >> 4) * 8 + x;      // m-tile 0..1023
    const int mbase = mtb * 64, nbase = nb * 64;

    // fragment base: row (l15 within 16-row frag), k-offset quad*8
    const _Float16* Arow = Qp + (size_t)(mbase + l15) * 512 + (quad << 3);
    const _Float16* Brow = Cp + (size_t)(nbase + l15) * 512 + (quad << 3);

    f32x4 acc[4][4] = {};

#pragma unroll 4
    for (int kc = 0; kc < 16; ++kc) {
        f16x8 af[4], bf[4];
#pragma unroll
        for (int t = 0; t < 4; ++t) {
            af[t] = *(const f16x8*)(Arow + (size_t)(t * 16) * 512 + kc * 32);
            bf[t] = *(const f16x8*)(Brow + (size_t)(t * 16) * 512 + kc * 32);
        }
#pragma unroll
        for (int mt = 0; mt < 4; ++mt)
#pragma unroll
            for (int nt = 0; nt < 4; ++nt)
                acc[mt][nt] = __builtin_amdgcn_mfma_f32_16x16x32_f16(
                    af[mt], bf[nt], acc[mt][nt], 0, 0, 0);
    }

    // ---- per-row top-2 over this tile's 64 cols ----
    float rn[4];
#pragma unroll
    for (int nt = 0; nt < 4; ++nt)
        rn[nt] = rnorm[nbase + nt * 16 + l15];

#pragma unroll
    for (int mt = 0; mt < 4; ++mt) {
#pragma unroll
        for (int r = 0; r < 4; ++r) {
            float v1 = -3.0e38f, v2 = -3.0e38f; int i1 = INT_MAX;
#pragma unroll
            for (int nt = 0; nt < 4; ++nt) {
                float v = acc[mt][nt][r] * rn[nt];
                int   cc = nbase + nt * 16 + l15;
                if (v > v1) { v2 = v1; v1 = v; i1 = cc; }
                else { if (v > v2) v2 = v; if (v == v1 && cc < i1) i1 = cc; }
            }
            // butterfly over the 16 column-lanes (same rows)
#pragma unroll
            for (int mask = 1; mask < 16; mask <<= 1) {
                float ov1 = __shfl_xor(v1, mask, 64);
                int   oi1 = __shfl_xor(i1, mask, 64);
                float ov2 = __shfl_xor(v2, mask, 64);
                if (ov1 > v1) { v2 = fmaxf(v1, ov2); v1 = ov1; i1 = oi1; }
                else if (ov1 == v1) { v2 = v1; i1 = min(i1, oi1); }
                else { v2 = fmaxf(v2, ov1); }
            }
            if (l15 == 0) {
                const int row = mbase + mt * 16 + quad * 4 + r;
                const size_t g = (size_t)row * 16 + nb;
                pv1[g] = v1; pi1[g] = i1; pv2[g] = v2;
            }
        }
    }
}

// ---------------------------------------------------------------------------
// Merge the 16 per-chunk partials per row; write argmax; flag near-ties.
// ---------------------------------------------------------------------------
__global__ void merge_kernel(const float* __restrict__ pv1,
                             const int*   __restrict__ pi1,
                             const float* __restrict__ pv2,
                             float* __restrict__ assign_out,
                             int* __restrict__ rlist, int* __restrict__ rcount) {
    const int row = blockIdx.x * 256 + threadIdx.x;
    float v1 = -3.0e38f, v2 = -3.0e38f; int i1 = INT_MAX;
    const size_t b = (size_t)row * 16;
#pragma unroll
    for (int n = 0; n < 16; ++n) {
        float a1 = pv1[b + n]; int ai = pi1[b + n]; float a2 = pv2[b + n];
        if (a1 > v1)       { v2 = fmaxf(v1, a2); v1 = a1; i1 = ai; }
        else if (a1 == v1) { v2 = v1; i1 = min(i1, ai); }
        else               { v2 = fmaxf(v2, a1); }
    }
    assign_out[row] = (float)i1;
    if (v1 - v2 < MARGIN) {
        int p = atomicAdd(rcount, 1);
        rlist[p] = row;
    }
}

// ---------------------------------------------------------------------------
// Exact fp32 recompute for flagged rows (full 1024 centroids per row).
// Grid 512, 2 rows per block (each centroid row read once serves both),
// 4 protos in flight per wave iteration (ILP hides L2 latency).
// ---------------------------------------------------------------------------
__launch_bounds__(256)
__global__ void refine_kernel(const float* __restrict__ Q,
                              const float* __restrict__ C,
                              const float* __restrict__ rnorm,
                              const int* __restrict__ rlist,
                              const int* __restrict__ rcount,
                              float* __restrict__ assign_out) {
    __shared__ float wv[8];
    __shared__ int   wi[8];
    const int n = *rcount;
    const int wave = threadIdx.x >> 6, lane = threadIdx.x & 63;
    for (int it = blockIdx.x * 2; it < n; it += gridDim.x * 2) {
        const int rowA = rlist[it];
        const int rowB = rlist[(it + 1 < n) ? (it + 1) : it];  // dup ok (same value write)
        const float4* qrA = (const float4*)(Q + (size_t)rowA * ND);
        const float4* qrB = (const float4*)(Q + (size_t)rowB * ND);
        float4 qa  = qrA[lane], qa2 = qrA[lane + 64];
        float4 qb  = qrB[lane], qb2 = qrB[lane + 64];
        float bestA = -3.0e38f, bestB = -3.0e38f;
        int   biA = INT_MAX,    biB = INT_MAX;
        for (int i = 0; i < 64; ++i) {
            const int p0 = i * 16 + wave * 4;   // ascending p within each wave
            float sA[4], sB[4];
#pragma unroll
            for (int jj = 0; jj < 4; ++jj) {
                const float4* cr = (const float4*)(C + (size_t)(p0 + jj) * ND);
                float4 b = cr[lane], b2 = cr[lane + 64];
                sA[jj] = qa.x * b.x + qa.y * b.y + qa.z * b.z + qa.w * b.w
                       + qa2.x * b2.x + qa2.y * b2.y + qa2.z * b2.z + qa2.w * b2.w;
                sB[jj] = qb.x * b.x + qb.y * b.y + qb.z * b.z + qb.w * b.w
                       + qb2.x * b2.x + qb2.y * b2.y + qb2.z * b2.z + qb2.w * b2.w;
            }
#pragma unroll
            for (int m = 1; m < 64; m <<= 1) {
#pragma unroll
                for (int jj = 0; jj < 4; ++jj) {
                    sA[jj] += __shfl_xor(sA[jj], m, 64);
                    sB[jj] += __shfl_xor(sB[jj], m, 64);
                }
            }
#pragma unroll
            for (int jj = 0; jj < 4; ++jj) {
                float rnv = rnorm[p0 + jj];
                float vA = sA[jj] * rnv, vB = sB[jj] * rnv;
                if (vA > bestA) { bestA = vA; biA = p0 + jj; }  // first-max wins
                if (vB > bestB) { bestB = vB; biB = p0 + jj; }
            }
        }
        __syncthreads();  // protect wv/wi reuse across row iterations
        if (lane == 0) {
            wv[wave] = bestA;     wi[wave] = biA;
            wv[4 + wave] = bestB; wi[4 + wave] = biB;
        }
        __syncthreads();
        if (threadIdx.x == 0) {
            float bv = wv[0]; int b0 = wi[0];
            for (int w = 1; w < 4; ++w)
                if (wv[w] > bv || (wv[w] == bv && wi[w] < b0)) { bv = wv[w]; b0 = wi[w]; }
            assign_out[rowA] = (float)b0;
        }
        if (threadIdx.x == 64) {
            float bv = wv[4]; int b0 = wi[4];
            for (int w = 5; w < 8; ++w)
                if (wv[w] > bv || (wv[w] == bv && wi[w] < b0)) { bv = wv[w]; b0 = wi[w]; }
            assign_out[rowB] = (float)b0;
        }
    }
}

// ---------------------------------------------------------------------------
// ctx gather + routing row write (zeros fused with the single 1.0).
// Covers the entire routing region, so no separate memset is needed.
// ---------------------------------------------------------------------------
__global__ void scatter_kernel(const float* __restrict__ cent,
                               const float* __restrict__ assign,
                               float* __restrict__ ctx,
                               float* __restrict__ routing) {
    const int q    = blockIdx.x * 2 + (threadIdx.x >> 7);
    const int lane = threadIdx.x & 127;
    const int ci   = (int)assign[q];
    const float4* src = (const float4*)(cent + (size_t)ci * ND);
    ((float4*)(ctx + (size_t)q * ND))[lane] = src[lane];
    float4 z1 = {0.f, 0.f, 0.f, 0.f};
    float4 z2 = {0.f, 0.f, 0.f, 0.f};
    if ((ci >> 2) == lane)        ((float*)&z1)[ci & 3] = 1.0f;
    if ((ci >> 2) == lane + 128)  ((float*)&z2)[ci & 3] = 1.0f;
    float4* rr = (float4*)(routing + (size_t)q * NP);
    rr[lane]       = z1;
    rr[lane + 128] = z2;
}

// ---------------------------------------------------------------------------
extern "C" void kernel_launch(void* const* d_in, const int* in_sizes, int n_in,
                              void* d_out, int out_size, void* d_ws, size_t ws_size,
                              hipStream_t stream) {
    const float* query = (const float*)d_in[0];   // (B, D) fp32
    const float* cent  = (const float*)d_in[1];   // (P, D) fp32

    float* out        = (float*)d_out;
    float* ctx        = out;                       // B*D
    float* assign_out = out + (size_t)NB * ND;     // B
    float* routing    = assign_out + NB;           // B*P (268 MB)

    // All bulky scratch lives inside the routing region; it is fully
    // overwritten by scatter_kernel at the end. d_ws is unused.
    char* scratch = (char*)routing;
    _Float16* Qp    = (_Float16*)(scratch);                       // 67,108,864 B
    _Float16* Cp    = (_Float16*)(scratch + 67108864);            //  1,048,576 B
    float*    rnorm = (float*)   (scratch + 68157440);            //      4,096 B
    float*    pv1   = (float*)   (scratch + 68161536);            //  4,194,304 B
    int*      pi1   = (int*)     (scratch + 72355840);            //  4,194,304 B
    float*    pv2   = (float*)   (scratch + 76550144);            //  4,194,304 B
    int*      rlist = (int*)     (scratch + 80744448);            //    262,144 B
    int*      rcount= (int*)     (scratch + 81006592);            //          4 B

    hipMemsetAsync(rcount, 0, sizeof(int), stream);

    centroid_rnorm_kernel<<<NP / 4, 256, 0, stream>>>(cent, rnorm);
    convertC_kernel<<<NP * ND / 8 / 256, 256, 0, stream>>>(cent, Cp);
    convertQ_kernel<<<NB * (ND / 8) / 256, 256, 0, stream>>>(query, Qp);
    gemm_top2_kernel<<<16384, 64, 0, stream>>>(Qp, Cp, rnorm, pv1, pi1, pv2);
    merge_kernel<<<NB / 256, 256, 0, stream>>>(pv1, pi1, pv2, assign_out, rlist, rcount);
    refine_kernel<<<512, 256, 0, stream>>>(query, cent, rnorm, rlist, rcount, assign_out);
    scatter_kernel<<<NB / 2, 256, 0, stream>>>(cent, assign_out, ctx, routing);
}

// Round 6
// 746.066 us; speedup vs baseline: 1.1437x; 1.1437x over previous
//
#include <hip/hip_runtime.h>
#include <hip/hip_bf16.h>
#include <climits>
#include <cstdint>

#define NB 65536   // batch
#define NP 1024    // prototypes
#define ND 512     // embed dim

// Hi-only f16 GEMM error (scaled units) has std ~4e-4; 4e-3 is ~7 sigma on the
// pairwise difference -> rows with approx top-2 gap below this get exact fp32
// recompute. Expected flagged rows ~1-2% of B.
#define MARGIN 4e-3f

typedef _Float16 f16x8 __attribute__((ext_vector_type(8)));
typedef float    f32x4 __attribute__((ext_vector_type(4)));

__device__ inline void load_lds16(const void* g, void* l) {
    __builtin_amdgcn_global_load_lds(
        (const __attribute__((address_space(1))) void*)g,
        (__attribute__((address_space(3))) void*)l, 16, 0, 0);
}

// ---------------------------------------------------------------------------
// rnorm[p] = 1 / max(||c_p||, 1e-12). One wave per row.
// ---------------------------------------------------------------------------
__global__ void centroid_rnorm_kernel(const float* __restrict__ cent,
                                      float* __restrict__ rnorm) {
    const int row  = blockIdx.x * 4 + (threadIdx.x >> 6);
    const int lane = threadIdx.x & 63;
    const float4* cr = (const float4*)(cent + (size_t)row * ND);
    float4 a = cr[2 * lane];
    float4 b = cr[2 * lane + 1];
    float s = a.x * a.x + a.y * a.y + a.z * a.z + a.w * a.w
            + b.x * b.x + b.y * b.y + b.z * b.z + b.w * b.w;
#pragma unroll
    for (int off = 32; off > 0; off >>= 1)
        s += __shfl_down(s, off, 64);
    if (lane == 0)
        rnorm[row] = 1.0f / fmaxf(sqrtf(s), 1e-12f);
}

// ---------------------------------------------------------------------------
// fp32 -> f16 (hi only) converters.
// Qp layout: 65536 x 512 f16.   Cp layout: 1024 x 512 f16.
// ---------------------------------------------------------------------------
__global__ void convertQ_kernel(const float* __restrict__ Q,
                                _Float16* __restrict__ Qp) {
    const size_t t = (size_t)blockIdx.x * 256 + threadIdx.x;  // 8 elems/thread
    const size_t base = t * 8;
    const float4* s = (const float4*)(Q + base);
    float4 x0 = s[0], x1 = s[1];
    float xs[8] = {x0.x, x0.y, x0.z, x0.w, x1.x, x1.y, x1.z, x1.w};
    f16x8 hi;
#pragma unroll
    for (int i = 0; i < 8; ++i)
        hi[i] = (_Float16)xs[i];
    *(f16x8*)(Qp + base) = hi;
}

__global__ void convertC_kernel(const float* __restrict__ C,
                                _Float16* __restrict__ Cp) {
    const size_t t = (size_t)blockIdx.x * 256 + threadIdx.x;
    const size_t base = t * 8;
    const float4* s = (const float4*)(C + base);
    float4 x0 = s[0], x1 = s[1];
    float xs[8] = {x0.x, x0.y, x0.z, x0.w, x1.x, x1.y, x1.z, x1.w};
    f16x8 hi;
#pragma unroll
    for (int i = 0; i < 8; ++i)
        hi[i] = (_Float16)xs[i];
    *(f16x8*)(Cp + base) = hi;
}

// ---------------------------------------------------------------------------
// 256x256 multi-phase MFMA GEMM (T2+T3+T4+T5), K=512, fused top-2.
//
// 512 threads = 8 waves (2M x 4N); per-wave output 128x64 (acc[8][4] f32x4).
// LDS: A,B double-buffered 256x64 f16 tiles = 128 KB total (1 block/CU).
// Prefetch 2 K-tiles deep via global_load_lds; counted s_waitcnt vmcnt(8)
// at iter top (never 0 until the last tile) keeps next tile's 8 loads in
// flight across barriers. Per K-tile, 4 compute phases with interleaved
// ds_read/MFMA quadrants {A0B0, A0B1(+B1 reads), A1B1(+A1 reads), A1B0},
// each wrapped in setprio(1)/(0) + s_barrier (wave role-split).
// Slot-XOR LDS swizzle (verified round 3): LDS[row][slot] holds data col
// slot ^ (row&7); read side applies the same XOR. Bank-conflict-free.
//
// Grid 1024 = 256 m-blocks x 4 n-blocks, XCD-swizzled (x = bid&7 owns
// m-blocks {x, x+8,...}, n fastest -> A-tile L2-reuse within an XCD).
// Per (row, 64-col chunk): partial {v1, i1, v2}, 16 per row.
// ---------------------------------------------------------------------------
__launch_bounds__(512, 2)
__global__ void gemm_top2_kernel(const _Float16* __restrict__ Qp,
                                 const _Float16* __restrict__ Cp,
                                 const float* __restrict__ rnorm,
                                 float* __restrict__ pv1,
                                 int*   __restrict__ pi1,
                                 float* __restrict__ pv2) {
    __shared__ __align__(16) _Float16 a_s[2][256 * 64];  // 2 x 32 KB
    __shared__ __align__(16) _Float16 b_s[2][256 * 64];  // 2 x 32 KB

    const int tid  = threadIdx.x;
    const int wave = tid >> 6, lane = tid & 63;
    const int quad = lane >> 4, l15 = lane & 15;
    const int sx   = l15 & 7;

    // XCD-contiguous swizzle over grid 1024 = 8 * 128.
    const int bid = blockIdx.x;
    const int x = bid & 7, j = bid >> 3;
    const int nbb = j & 3;                 // n-block 0..3
    const int mb  = (j >> 2) * 8 + x;      // m-block 0..255
    const int mbA = mb * 256, nbB = nbb * 256;

    const int wm = wave >> 2, wn = wave & 3;   // 2M x 4N wave grid

    f32x4 acc[8][4] = {};

    // stage one K-tile (A 32KB + B 32KB) into buffer bb: 8 glds per thread.
    // LDS[row][slot] <- src col (slot ^ (row&7)); dst linear in tid (16B/lane).
    const int rowi = tid >> 3;             // 0..63
    const int slot = tid & 7;
    auto STAGE = [&](int tt, int bb) {
        const int kbase = tt << 6;
#pragma unroll
        for (int seg = 0; seg < 4; ++seg) {
            const int lr = seg * 64 + rowi;
            const int sc = ((slot ^ (lr & 7)) << 3);
            load_lds16(Qp + (size_t)(mbA + lr) * 512 + kbase + sc,
                       a_s[bb] + lr * 64 + slot * 8);
        }
#pragma unroll
        for (int seg = 0; seg < 4; ++seg) {
            const int lr = seg * 64 + rowi;
            const int sc = ((slot ^ (lr & 7)) << 3);
            load_lds16(Cp + (size_t)(nbB + lr) * 512 + kbase + sc,
                       b_s[bb] + lr * 64 + slot * 8);
        }
    };

    STAGE(0, 0);
    STAGE(1, 1);

#pragma unroll 1
    for (int t = 0; t < 8; ++t) {
        const int cur = t & 1;
        // wait tile t's 8 loads (per-wave); leave tile t+1's in flight.
        if (t < 7) asm volatile("s_waitcnt vmcnt(8)" ::: "memory");
        else       asm volatile("s_waitcnt vmcnt(0)" ::: "memory");
        __builtin_amdgcn_s_barrier();      // buf[cur] ready for all waves

        const _Float16* As = a_s[cur];
        const _Float16* Bs = b_s[cur];

        f16x8 af[4][2], bf0[2][2], bf1[2][2];

        // ---- phase 0: load A0 (8) + B0 (4); compute A0 x B0 ----
#pragma unroll
        for (int mt = 0; mt < 4; ++mt)
#pragma unroll
            for (int k = 0; k < 2; ++k)
                af[mt][k] = *(const f16x8*)&As[(wm * 128 + mt * 16 + l15) * 64
                                              + (((k * 4 + quad) ^ sx) << 3)];
#pragma unroll
        for (int nt = 0; nt < 2; ++nt)
#pragma unroll
            for (int k = 0; k < 2; ++k)
                bf0[nt][k] = *(const f16x8*)&Bs[(wn * 64 + nt * 16 + l15) * 64
                                               + (((k * 4 + quad) ^ sx) << 3)];
        __builtin_amdgcn_s_setprio(1);
#pragma unroll
        for (int mt = 0; mt < 4; ++mt)
#pragma unroll
            for (int nt = 0; nt < 2; ++nt)
#pragma unroll
                for (int k = 0; k < 2; ++k)
                    acc[mt][nt] = __builtin_amdgcn_mfma_f32_16x16x32_f16(
                        af[mt][k], bf0[nt][k], acc[mt][nt], 0, 0, 0);
        __builtin_amdgcn_s_setprio(0);
        __builtin_amdgcn_s_barrier();

        // ---- phase 1: load B1 (4); compute A0 x B1 ----
#pragma unroll
        for (int nt = 0; nt < 2; ++nt)
#pragma unroll
            for (int k = 0; k < 2; ++k)
                bf1[nt][k] = *(const f16x8*)&Bs[(wn * 64 + 32 + nt * 16 + l15) * 64
                                               + (((k * 4 + quad) ^ sx) << 3)];
        __builtin_amdgcn_s_setprio(1);
#pragma unroll
        for (int mt = 0; mt < 4; ++mt)
#pragma unroll
            for (int nt = 0; nt < 2; ++nt)
#pragma unroll
                for (int k = 0; k < 2; ++k)
                    acc[mt][2 + nt] = __builtin_amdgcn_mfma_f32_16x16x32_f16(
                        af[mt][k], bf1[nt][k], acc[mt][2 + nt], 0, 0, 0);
        __builtin_amdgcn_s_setprio(0);
        __builtin_amdgcn_s_barrier();

        // ---- phase 2: load A1 (8, reuse af regs); compute A1 x B1 ----
#pragma unroll
        for (int mt = 0; mt < 4; ++mt)
#pragma unroll
            for (int k = 0; k < 2; ++k)
                af[mt][k] = *(const f16x8*)&As[(wm * 128 + 64 + mt * 16 + l15) * 64
                                              + (((k * 4 + quad) ^ sx) << 3)];
        __builtin_amdgcn_s_setprio(1);
#pragma unroll
        for (int mt = 0; mt < 4; ++mt)
#pragma unroll
            for (int nt = 0; nt < 2; ++nt)
#pragma unroll
                for (int k = 0; k < 2; ++k)
                    acc[4 + mt][2 + nt] = __builtin_amdgcn_mfma_f32_16x16x32_f16(
                        af[mt][k], bf1[nt][k], acc[4 + mt][2 + nt], 0, 0, 0);
        __builtin_amdgcn_s_setprio(0);
        __builtin_amdgcn_s_barrier();

        // ---- phase 3: no loads; compute A1 x B0 (bf0 still live) ----
        __builtin_amdgcn_s_setprio(1);
#pragma unroll
        for (int mt = 0; mt < 4; ++mt)
#pragma unroll
            for (int nt = 0; nt < 2; ++nt)
#pragma unroll
                for (int k = 0; k < 2; ++k)
                    acc[4 + mt][nt] = __builtin_amdgcn_mfma_f32_16x16x32_f16(
                        af[mt][k], bf0[nt][k], acc[4 + mt][nt], 0, 0, 0);
        __builtin_amdgcn_s_setprio(0);
        __builtin_amdgcn_s_barrier();      // release buf[cur]

        if (t + 2 < 8) STAGE(t + 2, cur);  // into just-released buffer
    }

    // ---- epilogue: per-row top-2 over this wave's 64-col chunk ----
    float rn[4];
#pragma unroll
    for (int nt = 0; nt < 4; ++nt)
        rn[nt] = rnorm[nbB + wn * 64 + nt * 16 + l15];

#pragma unroll
    for (int mt = 0; mt < 8; ++mt) {
#pragma unroll
        for (int r = 0; r < 4; ++r) {
            float v1 = -3.0e38f, v2 = -3.0e38f; int i1 = INT_MAX;
#pragma unroll
            for (int nt = 0; nt < 4; ++nt) {
                float v = acc[mt][nt][r] * rn[nt];
                int   cc = nbB + wn * 64 + nt * 16 + l15;
                if (v > v1) { v2 = v1; v1 = v; i1 = cc; }
                else { if (v > v2) v2 = v; if (v == v1 && cc < i1) i1 = cc; }
            }
            // butterfly over the 16 column-lanes (same rows)
#pragma unroll
            for (int mask = 1; mask < 16; mask <<= 1) {
                float ov1 = __shfl_xor(v1, mask, 64);
                int   oi1 = __shfl_xor(i1, mask, 64);
                float ov2 = __shfl_xor(v2, mask, 64);
                if (ov1 > v1) { v2 = fmaxf(v1, ov2); v1 = ov1; i1 = oi1; }
                else if (ov1 == v1) { v2 = v1; i1 = min(i1, oi1); }
                else { v2 = fmaxf(v2, ov1); }
            }
            if (l15 == 0) {
                const int row = mbA + wm * 128 + mt * 16 + quad * 4 + r;
                const size_t g = (size_t)row * 16 + (nbb * 4 + wn);
                pv1[g] = v1; pi1[g] = i1; pv2[g] = v2;
            }
        }
    }
}

// ---------------------------------------------------------------------------
// Merge the 16 per-chunk partials per row; write argmax; flag near-ties.
// ---------------------------------------------------------------------------
__global__ void merge_kernel(const float* __restrict__ pv1,
                             const int*   __restrict__ pi1,
                             const float* __restrict__ pv2,
                             float* __restrict__ assign_out,
                             int* __restrict__ rlist, int* __restrict__ rcount) {
    const int row = blockIdx.x * 256 + threadIdx.x;
    float v1 = -3.0e38f, v2 = -3.0e38f; int i1 = INT_MAX;
    const size_t b = (size_t)row * 16;
#pragma unroll
    for (int n = 0; n < 16; ++n) {
        float a1 = pv1[b + n]; int ai = pi1[b + n]; float a2 = pv2[b + n];
        if (a1 > v1)       { v2 = fmaxf(v1, a2); v1 = a1; i1 = ai; }
        else if (a1 == v1) { v2 = v1; i1 = min(i1, ai); }
        else               { v2 = fmaxf(v2, a1); }
    }
    assign_out[row] = (float)i1;
    if (v1 - v2 < MARGIN) {
        int p = atomicAdd(rcount, 1);
        rlist[p] = row;
    }
}

// ---------------------------------------------------------------------------
// Exact fp32 recompute for flagged rows (full 1024 centroids per row).
// Grid 512, 2 rows per block (each centroid row read once serves both),
// 4 protos in flight per wave iteration (ILP hides L2 latency).
// ---------------------------------------------------------------------------
__launch_bounds__(256)
__global__ void refine_kernel(const float* __restrict__ Q,
                              const float* __restrict__ C,
                              const float* __restrict__ rnorm,
                              const int* __restrict__ rlist,
                              const int* __restrict__ rcount,
                              float* __restrict__ assign_out) {
    __shared__ float wv[8];
    __shared__ int   wi[8];
    const int n = *rcount;
    const int wave = threadIdx.x >> 6, lane = threadIdx.x & 63;
    for (int it = blockIdx.x * 2; it < n; it += gridDim.x * 2) {
        const int rowA = rlist[it];
        const int rowB = rlist[(it + 1 < n) ? (it + 1) : it];  // dup ok (same value write)
        const float4* qrA = (const float4*)(Q + (size_t)rowA * ND);
        const float4* qrB = (const float4*)(Q + (size_t)rowB * ND);
        float4 qa  = qrA[lane], qa2 = qrA[lane + 64];
        float4 qb  = qrB[lane], qb2 = qrB[lane + 64];
        float bestA = -3.0e38f, bestB = -3.0e38f;
        int   biA = INT_MAX,    biB = INT_MAX;
        for (int i = 0; i < 64; ++i) {
            const int p0 = i * 16 + wave * 4;   // ascending p within each wave
            float sA[4], sB[4];
#pragma unroll
            for (int jj = 0; jj < 4; ++jj) {
                const float4* cr = (const float4*)(C + (size_t)(p0 + jj) * ND);
                float4 b = cr[lane], b2 = cr[lane + 64];
                sA[jj] = qa.x * b.x + qa.y * b.y + qa.z * b.z + qa.w * b.w
                       + qa2.x * b2.x + qa2.y * b2.y + qa2.z * b2.z + qa2.w * b2.w;
                sB[jj] = qb.x * b.x + qb.y * b.y + qb.z * b.z + qb.w * b.w
                       + qb2.x * b2.x + qb2.y * b2.y + qb2.z * b2.z + qb2.w * b2.w;
            }
#pragma unroll
            for (int m = 1; m < 64; m <<= 1) {
#pragma unroll
                for (int jj = 0; jj < 4; ++jj) {
                    sA[jj] += __shfl_xor(sA[jj], m, 64);
                    sB[jj] += __shfl_xor(sB[jj], m, 64);
                }
            }
#pragma unroll
            for (int jj = 0; jj < 4; ++jj) {
                float rnv = rnorm[p0 + jj];
                float vA = sA[jj] * rnv, vB = sB[jj] * rnv;
                if (vA > bestA) { bestA = vA; biA = p0 + jj; }  // first-max wins
                if (vB > bestB) { bestB = vB; biB = p0 + jj; }
            }
        }
        __syncthreads();  // protect wv/wi reuse across row iterations
        if (lane == 0) {
            wv[wave] = bestA;     wi[wave] = biA;
            wv[4 + wave] = bestB; wi[4 + wave] = biB;
        }
        __syncthreads();
        if (threadIdx.x == 0) {
            float bv = wv[0]; int b0 = wi[0];
            for (int w = 1; w < 4; ++w)
                if (wv[w] > bv || (wv[w] == bv && wi[w] < b0)) { bv = wv[w]; b0 = wi[w]; }
            assign_out[rowA] = (float)b0;
        }
        if (threadIdx.x == 64) {
            float bv = wv[4]; int b0 = wi[4];
            for (int w = 5; w < 8; ++w)
                if (wv[w] > bv || (wv[w] == bv && wi[w] < b0)) { bv = wv[w]; b0 = wi[w]; }
            assign_out[rowB] = (float)b0;
        }
    }
}

// ---------------------------------------------------------------------------
// ctx gather + routing row write (zeros fused with the single 1.0).
// Covers the entire routing region, so no separate memset is needed.
// ---------------------------------------------------------------------------
__global__ void scatter_kernel(const float* __restrict__ cent,
                               const float* __restrict__ assign,
                               float* __restrict__ ctx,
                               float* __restrict__ routing) {
    const int q    = blockIdx.x * 2 + (threadIdx.x >> 7);
    const int lane = threadIdx.x & 127;
    const int ci   = (int)assign[q];
    const float4* src = (const float4*)(cent + (size_t)ci * ND);
    ((float4*)(ctx + (size_t)q * ND))[lane] = src[lane];
    float4 z1 = {0.f, 0.f, 0.f, 0.f};
    float4 z2 = {0.f, 0.f, 0.f, 0.f};
    if ((ci >> 2) == lane)        ((float*)&z1)[ci & 3] = 1.0f;
    if ((ci >> 2) == lane + 128)  ((float*)&z2)[ci & 3] = 1.0f;
    float4* rr = (float4*)(routing + (size_t)q * NP);
    rr[lane]       = z1;
    rr[lane + 128] = z2;
}

// ---------------------------------------------------------------------------
extern "C" void kernel_launch(void* const* d_in, const int* in_sizes, int n_in,
                              void* d_out, int out_size, void* d_ws, size_t ws_size,
                              hipStream_t stream) {
    const float* query = (const float*)d_in[0];   // (B, D) fp32
    const float* cent  = (const float*)d_in[1];   // (P, D) fp32

    float* out        = (float*)d_out;
    float* ctx        = out;                       // B*D
    float* assign_out = out + (size_t)NB * ND;     // B
    float* routing    = assign_out + NB;           // B*P (268 MB)

    // All bulky scratch lives inside the routing region; it is fully
    // overwritten by scatter_kernel at the end. d_ws is unused.
    char* scratch = (char*)routing;
    _Float16* Qp    = (_Float16*)(scratch);                       // 67,108,864 B
    _Float16* Cp    = (_Float16*)(scratch + 67108864);            //  1,048,576 B
    float*    rnorm = (float*)   (scratch + 68157440);            //      4,096 B
    float*    pv1   = (float*)   (scratch + 68161536);            //  4,194,304 B
    int*      pi1   = (int*)     (scratch + 72355840);            //  4,194,304 B
    float*    pv2   = (float*)   (scratch + 76550144);            //  4,194,304 B
    int*      rlist = (int*)     (scratch + 80744448);            //    262,144 B
    int*      rcount= (int*)     (scratch + 81006592);            //          4 B

    hipMemsetAsync(rcount, 0, sizeof(int), stream);

    centroid_rnorm_kernel<<<NP / 4, 256, 0, stream>>>(cent, rnorm);
    convertC_kernel<<<NP * ND / 8 / 256, 256, 0, stream>>>(cent, Cp);
    convertQ_kernel<<<NB * (ND / 8) / 256, 256, 0, stream>>>(query, Qp);
    gemm_top2_kernel<<<1024, 512, 0, stream>>>(Qp, Cp, rnorm, pv1, pi1, pv2);
    merge_kernel<<<NB / 256, 256, 0, stream>>>(pv1, pi1, pv2, assign_out, rlist, rcount);
    refine_kernel<<<512, 256, 0, stream>>>(query, cent, rnorm, rlist, rcount, assign_out);
    scatter_kernel<<<NB / 2, 256, 0, stream>>>(cent, assign_out, ctx, routing);
}